// Round 2
// baseline (1905.412 us; speedup 1.0000x reference)
//
#include <hip/hip_runtime.h>

typedef __attribute__((ext_vector_type(8))) __bf16 bf16x8;
typedef __attribute__((ext_vector_type(4))) float f32x4;
typedef unsigned short u16;
typedef unsigned int u32;

// ================= K1 LDS layout (bytes) =================
// wt : [64][384] bf16 stride 768, swz ^(row&7)<<4   (per-sec weight tile)
// vt : [64][128] bf16 stride 256, swz  -- OVERLAYS wt bytes 32768..49152
// qh : [80][64]  bf16 stride 128, swz
// kh : [80][64]  bf16 stride 128, swz
// P  : [80][128] bf16 stride 256, swz  -- OVERLAYS qh+kh
// tab: cos/sin [18][16] f32
#define WT_OFF 0
#define VT_OFF 32768
#define QH_OFF 49152
#define KH_OFF 59392
#define P_OFF  49152
#define TC_OFF 69632
#define TS_OFF 70784
#define SMEM1  71936

// ================= K2 LDS layout =================
#define A2_OFF 0        // [128][64] bf16 stride 128, swz : 16384
#define B2_OFF 16384    // [384][64] bf16 stride 128, swz : 49152
#define SMEM2  65536

__device__ __forceinline__ u16 f2bf(float x){
  u32 u = __float_as_uint(x);
  return (u16)((u + 0x7fffu + ((u >> 16) & 1u)) >> 16);
}

union FragU { uint4 u4; bf16x8 bf; };

__device__ __forceinline__ bf16x8 lds_frag(const unsigned char* smem, int off, int row, int strideB, int kElem){
  int byte = (row * strideB + kElem * 2) ^ ((row & 7) << 4);
  FragU f; f.u4 = *reinterpret_cast<const uint4*>(smem + off + byte);
  return f.bf;
}

typedef __attribute__((address_space(3))) unsigned char lds_u8;
typedef __attribute__((address_space(1))) const unsigned char g_u8;
__device__ __forceinline__ void glds16(const void* g, void* l){
  __builtin_amdgcn_global_load_lds((g_u8*)g, (lds_u8*)l, 16, 0, 0);
}

__global__ void prep_weights(const float* __restrict__ wq, const float* __restrict__ wp,
                             u16* __restrict__ wqb, u16* __restrict__ wpb){
  int i = blockIdx.x * 256 + threadIdx.x;
  wqb[i] = f2bf(wq[i]);              // grid sized exactly for 442368
  if (i < 147456) wpb[i] = f2bf(wp[i]);
}

// stage [64][384] bf16 weight slice into wt with inverse-swizzled source
__device__ __forceinline__ void stage_wt(const u16* wsec, unsigned char* base, int wave, int lane){
  #pragma unroll
  for (int it = 0; it < 10; ++it){
    if (it < 9 || wave < 3){                   // 3072 chunks total; tail = 3 waves
      int c = it * 320 + wave * 64 + lane;
      int row = c / 48;                        // 48 x 16B chunks per row
      int p = c - row * 48;
      int s = p ^ (row & 7);                   // inverse of read-side XOR swizzle
      glds16(wsec + (size_t)row * 384 + s * 8,
             base + WT_OFF + (it * 320 + wave * 64) * 16);
    }
  }
}

__launch_bounds__(320, 3)
__global__ void swin_attn(const float* __restrict__ x,
                          const float* __restrict__ bq,
                          const u16* __restrict__ wqb,
                          float* __restrict__ out)
{
  __shared__ __align__(16) unsigned char smem[SMEM1];
  unsigned char* base = smem;

  const int tid  = threadIdx.x;
  const int wave = tid >> 6;
  const int lane = tid & 63;
  const int l15  = lane & 15;
  const int lhi  = lane >> 4;

  const int wgid = blockIdx.x;       // b*1024 + wi*32 + wj
  const int bIdx = wgid >> 10;
  const int win  = wgid & 1023;
  const int wi   = win >> 5;
  const int wj   = win & 31;
  const bool maskWin = (wi == 31);

  float* tabc = reinterpret_cast<float*>(base + TC_OFF);
  float* tabs = reinterpret_cast<float*>(base + TS_OFF);
  if (tid < 288){
    int pos = tid >> 4, m = tid & 15;
    float pv = (pos < 6) ? (float)pos : (float)(pos - 6);
    float ang = pv * __expf(-(float)m * 0.5756462732485114f); // 10000^(-m/16)
    tabc[tid] = cosf(ang);
    tabs[tid] = sinf(ang);
  }

  // per-lane token (M-split: wave owns rows wave*16..+16)
  const int t = wave * 16 + l15;
  const bool tv = (t < 72);
  size_t xrow = 0;
  if (tv){
    int r = t / 12, cl = t - r * 12;
    int hh  = wi * 6 + r + 3;   if (hh  >= 192) hh  -= 192;
    int ww2 = wj * 12 + cl + 6; if (ww2 >= 384) ww2 -= 384;
    xrow = ((size_t)bIdx * 192 + hh) * 384 + ww2;
  }
  const float* xp = x + xrow * 384;

  // x fragments in registers: lane(l15=row, lhi=k-slice), frag[ks] = x[t][ks*32+lhi*8 ..+8]
  bf16x8 xfrag[12];
  #pragma unroll
  for (int ks = 0; ks < 12; ++ks){
    u32 a = 0, b = 0, c = 0, d = 0;
    if (tv){
      float4 f0 = *reinterpret_cast<const float4*>(xp + ks * 32 + lhi * 8);
      float4 f1 = *reinterpret_cast<const float4*>(xp + ks * 32 + lhi * 8 + 4);
      a = (u32)f2bf(f0.x) | ((u32)f2bf(f0.y) << 16);
      b = (u32)f2bf(f0.z) | ((u32)f2bf(f0.w) << 16);
      c = (u32)f2bf(f1.x) | ((u32)f2bf(f1.y) << 16);
      d = (u32)f2bf(f1.z) | ((u32)f2bf(f1.w) << 16);
    }
    FragU f; f.u4.x = a; f.u4.y = b; f.u4.z = c; f.u4.w = d;
    xfrag[ks] = f.bf;
  }

  float sv[5][4];                        // save_attn accum: [k-tile][r], q = qcol
  #pragma unroll
  for (int a2 = 0; a2 < 5; a2++)
    #pragma unroll
    for (int b2 = 0; b2 < 4; b2++) sv[a2][b2] = 0.0f;

  const int qcol = wave * 16 + l15;      // this lane's q token (== t)

  for (int h = 0; h < 6; ++h){
    // ===== QKV: three secs (q,k,v), M-split, weights staged in LDS =====
    #pragma unroll
    for (int sec = 0; sec < 3; ++sec){
      stage_wt(wqb + (size_t)(sec * 384 + h * 64) * 384, base, wave, lane);
      __syncthreads();                                   // stage visible

      f32x4 acc[4];
      #pragma unroll
      for (int nt = 0; nt < 4; ++nt) acc[nt] = 0.0f;
      #pragma unroll
      for (int ks = 0; ks < 12; ++ks){
        const int kEl = ks * 32 + lhi * 8;
        #pragma unroll
        for (int nt = 0; nt < 4; ++nt){
          bf16x8 bfr = lds_frag(base, WT_OFF, nt * 16 + l15, 768, kEl);
          acc[nt] = __builtin_amdgcn_mfma_f32_16x16x32_bf16(xfrag[ks], bfr, acc[nt], 0, 0, 0);
        }
      }

      if (sec == 2) __syncthreads();     // all wt reads done before vt overlays wt

      if (sec < 2){
        // bias + RoPE, store to qh/kh [t][ch]
        const int offD = (sec == 0) ? QH_OFF : KH_OFF;
        #pragma unroll
        for (int nt = 0; nt < 4; ++nt){
          const int chl = nt * 16 + l15;
          const float bias = bq[sec * 384 + h * 64 + chl];
          const int p  = chl >> 1;
          const int m  = p & 15;
          const bool isR = (p < 16);
          const bool ev  = ((chl & 1) == 0);
          #pragma unroll
          for (int r = 0; r < 4; ++r){
            const int tt = wave * 16 + lhi * 4 + r;
            float vb = acc[nt][r] + bias;
            float o  = __shfl_xor(vb, 1);
            int pos = isR ? (tt / 12) : (6 + tt - (tt / 12) * 12);
            float cc = tabc[pos * 16 + m], ss = tabs[pos * 16 + m];
            float nv = ev ? (vb * cc - o * ss) : (o * ss + vb * cc);
            if (sec == 0) nv *= 0.125f;
            int byte = (tt * 128 + chl * 2) ^ ((tt & 7) << 4);
            *reinterpret_cast<u16*>(base + offD + byte) = f2bf(nv);
          }
        }
      } else {
        // v: store transposed vt[ch][token], packed along tokens
        #pragma unroll
        for (int nt = 0; nt < 4; ++nt){
          const int chl = nt * 16 + l15;
          const float bias = bq[768 + h * 64 + chl];
          const int t0 = wave * 16 + lhi * 4;
          uint2 pk;
          pk.x = (u32)f2bf(acc[nt][0] + bias) | ((u32)f2bf(acc[nt][1] + bias) << 16);
          pk.y = (u32)f2bf(acc[nt][2] + bias) | ((u32)f2bf(acc[nt][3] + bias) << 16);
          int byte = (chl * 256 + t0 * 2) ^ ((chl & 7) << 4);
          *reinterpret_cast<uint2*>(base + VT_OFF + byte) = pk;
        }
      }
      __syncthreads();
    }

    // ===== QK^T (S^T orientation: C[i=k][j=q]) + softmax over k =====
    f32x4 pf[5];
    #pragma unroll
    for (int nt = 0; nt < 5; ++nt) pf[nt] = 0.0f;
    #pragma unroll
    for (int ks = 0; ks < 2; ++ks){
      const int kEl = ks * 32 + lhi * 8;
      bf16x8 qf = lds_frag(base, QH_OFF, qcol, 128, kEl);
      #pragma unroll
      for (int nt = 0; nt < 5; ++nt){
        bf16x8 kf = lds_frag(base, KH_OFF, nt * 16 + l15, 128, kEl);
        pf[nt] = __builtin_amdgcn_mfma_f32_16x16x32_bf16(kf, qf, pf[nt], 0, 0, 0);
      }
    }
    float mx = -1e30f;
    #pragma unroll
    for (int nt = 0; nt < 5; ++nt)
      #pragma unroll
      for (int r = 0; r < 4; ++r){
        const int kk = nt * 16 + lhi * 4 + r;
        bool valid = (kk < 72) && (!maskWin || ((kk < 36) == (qcol < 36)));
        float val = valid ? pf[nt][r] : -1e30f;
        pf[nt][r] = val;
        mx = fmaxf(mx, val);
      }
    mx = fmaxf(mx, __shfl_xor(mx, 16));
    mx = fmaxf(mx, __shfl_xor(mx, 32));
    float sm = 0.0f;
    #pragma unroll
    for (int nt = 0; nt < 5; ++nt)
      #pragma unroll
      for (int r = 0; r < 4; ++r){
        float e = __expf(pf[nt][r] - mx);
        pf[nt][r] = e; sm += e;
      }
    sm += __shfl_xor(sm, 16);
    sm += __shfl_xor(sm, 32);
    const float inv = 1.0f / sm;
    #pragma unroll
    for (int nt = 0; nt < 5; ++nt)
      #pragma unroll
      for (int r = 0; r < 4; ++r){
        float pv2 = pf[nt][r] * inv;
        pf[nt][r] = pv2;
        sv[nt][r] += pv2;
      }

    __syncthreads();                     // qh/kh reads done (P overlays them)

    // P[q][k] store, packed along k; zero-pad k=80..95
    #pragma unroll
    for (int nt = 0; nt < 5; ++nt){
      const int k0 = nt * 16 + lhi * 4;
      uint2 pk;
      pk.x = (u32)f2bf(pf[nt][0]) | ((u32)f2bf(pf[nt][1]) << 16);
      pk.y = (u32)f2bf(pf[nt][2]) | ((u32)f2bf(pf[nt][3]) << 16);
      int byte = (qcol * 256 + k0 * 2) ^ ((qcol & 7) << 4);
      *reinterpret_cast<uint2*>(base + P_OFF + byte) = pk;
    }
    {
      int byte = (qcol * 256 + (80 + lhi * 4) * 2) ^ ((qcol & 7) << 4);
      uint2 z; z.x = 0; z.y = 0;
      *reinterpret_cast<uint2*>(base + P_OFF + byte) = z;
    }
    __syncthreads();                     // P visible

    // ===== PV: C[i=ch][j=q]; write attnout bf16 into out-row first halves =====
    f32x4 oacc[4];
    #pragma unroll
    for (int nt = 0; nt < 4; ++nt) oacc[nt] = 0.0f;
    #pragma unroll
    for (int ks = 0; ks < 3; ++ks){
      const int kEl = ks * 32 + lhi * 8;
      bf16x8 pfr = lds_frag(base, P_OFF, qcol, 256, kEl);
      #pragma unroll
      for (int nt = 0; nt < 4; ++nt){
        bf16x8 vf = lds_frag(base, VT_OFF, nt * 16 + l15, 256, kEl);
        oacc[nt] = __builtin_amdgcn_mfma_f32_16x16x32_bf16(vf, pfr, oacc[nt], 0, 0, 0);
      }
    }
    if (tv){
      u16* ao = (u16*)out + xrow * 768 + h * 64;
      #pragma unroll
      for (int nt = 0; nt < 4; ++nt){
        uint2 pk;
        pk.x = (u32)f2bf(oacc[nt][0]) | ((u32)f2bf(oacc[nt][1]) << 16);
        pk.y = (u32)f2bf(oacc[nt][2]) | ((u32)f2bf(oacc[nt][3]) << 16);
        *reinterpret_cast<uint2*>(ao + nt * 16 + lhi * 4) = pk;
      }
    }
    __syncthreads();                     // P/vt reads done before next stage
  } // heads

  // ===== save_attn = mean over heads: so[q*72 + k] =====
  if (tv){
    float* so = out + 56623104ull + (size_t)wgid * 5184 + (size_t)qcol * 72;
    const float c6 = 1.0f / 6.0f;
    #pragma unroll
    for (int nt = 0; nt < 4; ++nt){
      float4 v4; v4.x = sv[nt][0]*c6; v4.y = sv[nt][1]*c6; v4.z = sv[nt][2]*c6; v4.w = sv[nt][3]*c6;
      *reinterpret_cast<float4*>(so + nt * 16 + lhi * 4) = v4;
    }
    if (lhi < 2){
      float4 v4; v4.x = sv[4][0]*c6; v4.y = sv[4][1]*c6; v4.z = sv[4][2]*c6; v4.w = sv[4][3]*c6;
      *reinterpret_cast<float4*>(so + 64 + lhi * 4) = v4;
    }
  }
}

// ===== K2: out-projection GEMM, in-place (reads bf16 row halves, writes f32 rows) =====
__launch_bounds__(512, 2)
__global__ void proj_gemm(const u16* __restrict__ wpb, const float* __restrict__ bp,
                          float* __restrict__ out)
{
  __shared__ __align__(16) unsigned char smem[SMEM2];
  unsigned char* base = smem;

  const int tid  = threadIdx.x;
  const int wave = tid >> 6;
  const int lane = tid & 63;
  const int l15  = lane & 15;
  const int lhi  = lane >> 4;
  const int wr   = wave >> 2;            // 0..1: row half
  const int wc   = wave & 3;             // 0..3: col quarter (96 cols)
  const size_t row0 = (size_t)blockIdx.x * 128;
  const u16* aog = (const u16*)out;      // bf16 attnout at row*768

  f32x4 acc[4][6];
  #pragma unroll
  for (int mt = 0; mt < 4; ++mt)
    #pragma unroll
    for (int nt = 0; nt < 6; ++nt) acc[mt][nt] = 0.0f;

  for (int kk = 0; kk < 6; ++kk){
    // stage A [128][64]: 1024 chunks
    #pragma unroll
    for (int it = 0; it < 2; ++it){
      int c = it * 512 + wave * 64 + lane;
      int rrow = c >> 3, p = c & 7;
      int s = p ^ (rrow & 7);
      glds16(aog + (row0 + rrow) * 768 + kk * 64 + s * 8,
             base + A2_OFF + (it * 512 + wave * 64) * 16);
    }
    // stage B [384][64]: 3072 chunks
    #pragma unroll
    for (int it = 0; it < 6; ++it){
      int c = it * 512 + wave * 64 + lane;
      int n = c >> 3, p = c & 7;
      int s = p ^ (n & 7);
      glds16(wpb + (size_t)n * 384 + kk * 64 + s * 8,
             base + B2_OFF + (it * 512 + wave * 64) * 16);
    }
    __syncthreads();
    #pragma unroll
    for (int ks = 0; ks < 2; ++ks){
      const int kEl = ks * 32 + lhi * 8;
      bf16x8 af[4], bf[6];
      #pragma unroll
      for (int mt = 0; mt < 4; ++mt)
        af[mt] = lds_frag(base, A2_OFF, wr * 64 + mt * 16 + l15, 128, kEl);
      #pragma unroll
      for (int nt = 0; nt < 6; ++nt)
        bf[nt] = lds_frag(base, B2_OFF, wc * 96 + nt * 16 + l15, 128, kEl);
      #pragma unroll
      for (int mt = 0; mt < 4; ++mt)
        #pragma unroll
        for (int nt = 0; nt < 6; ++nt)
          acc[mt][nt] = __builtin_amdgcn_mfma_f32_16x16x32_bf16(af[mt], bf[nt], acc[mt][nt], 0, 0, 0);
    }
    __syncthreads();
  }

  float bpv[6];
  #pragma unroll
  for (int nt = 0; nt < 6; ++nt) bpv[nt] = bp[wc * 96 + nt * 16 + l15];
  #pragma unroll
  for (int mt = 0; mt < 4; ++mt)
    #pragma unroll
    for (int nt = 0; nt < 6; ++nt){
      const int ch = wc * 96 + nt * 16 + l15;
      #pragma unroll
      for (int r = 0; r < 4; ++r){
        size_t grow = row0 + wr * 64 + mt * 16 + lhi * 4 + r;
        out[grow * 384 + ch] = acc[mt][nt][r] + bpv[nt];
      }
    }
}

extern "C" void kernel_launch(void* const* d_in, const int* in_sizes, int n_in,
                              void* d_out, int out_size, void* d_ws, size_t ws_size,
                              hipStream_t stream)
{
  const float* x  = (const float*)d_in[0];
  const float* wq = (const float*)d_in[1];
  const float* bq = (const float*)d_in[2];
  const float* wp = (const float*)d_in[3];
  const float* bp = (const float*)d_in[4];
  float* out = (float*)d_out;

  u16* wqb = (u16*)d_ws;                              // 442368 bf16
  u16* wpb = (u16*)((char*)d_ws + 442368 * 2);        // 147456 bf16

  prep_weights<<<1728, 256, 0, stream>>>(wq, wp, wqb, wpb);
  swin_attn<<<2048, 320, 0, stream>>>(x, bq, wqb, out);
  proj_gemm<<<1152, 512, 0, stream>>>(wpb, bp, out);
}

// Round 3
// 1170.838 us; speedup vs baseline: 1.6274x; 1.6274x over previous
//
#include <hip/hip_runtime.h>

typedef __attribute__((ext_vector_type(8))) __bf16 bf16x8;
typedef __attribute__((ext_vector_type(4))) float f32x4;
typedef unsigned short u16;
typedef unsigned int u32;

__device__ __forceinline__ u16 f2bf(float x){
  u32 u = __float_as_uint(x);
  return (u16)((u + 0x7fffu + ((u >> 16) & 1u)) >> 16);
}
__device__ __forceinline__ u32 pkbf(float lo, float hi){
  u32 r; asm("v_cvt_pk_bf16_f32 %0, %1, %2" : "=v"(r) : "v"(lo), "v"(hi)); return r;
}

union FragU { uint4 u4; bf16x8 bf; };

__device__ __forceinline__ bf16x8 lds_frag(const unsigned char* smem, int off, int row, int strideB, int kElem){
  int byte = (row * strideB + kElem * 2) ^ ((row & 7) << 4);
  FragU f; f.u4 = *reinterpret_cast<const uint4*>(smem + off + byte);
  return f.bf;
}

typedef __attribute__((address_space(3))) unsigned char lds_u8;
typedef __attribute__((address_space(1))) const unsigned char g_u8;
__device__ __forceinline__ void glds16(const void* g, void* l){
  __builtin_amdgcn_global_load_lds((g_u8*)g, (lds_u8*)l, 16, 0, 0);
}

__global__ void prep_weights(const float* __restrict__ wq, const float* __restrict__ wp,
                             u16* __restrict__ wqb, u16* __restrict__ wpb){
  int i = blockIdx.x * 256 + threadIdx.x;
  wqb[i] = f2bf(wq[i]);              // grid sized exactly for 442368
  if (i < 147456) wpb[i] = f2bf(wp[i]);
}

// ============ K2: q,k GEMM with fused bias+RoPE(+scale), bf16 store into out ============
// M=147456 (row-major tokens), N=384, K=384; blockIdx.y: 0=q, 1=k.
#define QA_OFF 0        // [128][64] bf16 swz : 16384
#define QB_OFF 16384    // [384][64] bf16 swz : 49152 -> 65536
#define QTC    65536    // 288 f32
#define QTS    66688    // 288 f32 -> 67840
__launch_bounds__(512, 2)
__global__ void qk_gemm(const float* __restrict__ x, const u16* __restrict__ wqb,
                        const float* __restrict__ bq, float* __restrict__ out)
{
  __shared__ __align__(16) unsigned char smem[67840];
  const int tid  = threadIdx.x;
  const int wave = tid >> 6;
  const int lane = tid & 63;
  const int l15  = lane & 15;
  const int lhi  = lane >> 4;
  const int wr   = wave >> 2;           // 0..1 : 64-row half
  const int wc   = wave & 3;            // 0..3 : 96-col quarter
  const int bx   = blockIdx.x;
  const int sec  = blockIdx.y;          // 0=q, 1=k
  const size_t row0 = (size_t)bx * 128;
  const int a    = bx / 3;              // global image-row (const per block)
  const int bcol = bx - 3 * a;
  const int hh   = a % 192;
  const int r6   = (hh + 3) % 6;        // window-row (const per block)

  float* tabc = reinterpret_cast<float*>(smem + QTC);
  float* tabs = reinterpret_cast<float*>(smem + QTS);
  if (tid < 288){
    int pos = tid >> 4, m = tid & 15;
    float pv = (pos < 6) ? (float)pos : (float)(pos - 6);
    float ang = pv * __expf(-(float)m * 0.5756462732485114f); // 10000^(-m/16)
    tabc[tid] = cosf(ang);
    tabs[tid] = sinf(ang);
  }

  f32x4 acc[4][6];
  #pragma unroll
  for (int mt = 0; mt < 4; ++mt)
    #pragma unroll
    for (int nt = 0; nt < 6; ++nt) acc[mt][nt] = 0.0f;

  for (int kk = 0; kk < 6; ++kk){
    // stage A: f32 -> bf16 reg-staging, swizzled [128][64]
    {
      int row = tid >> 2;
      int c0  = (tid & 3) << 4;
      const float* src = x + (row0 + row) * 384 + kk * 64 + c0;
      float4 a0 = *reinterpret_cast<const float4*>(src);
      float4 a1 = *reinterpret_cast<const float4*>(src + 4);
      float4 a2 = *reinterpret_cast<const float4*>(src + 8);
      float4 a3 = *reinterpret_cast<const float4*>(src + 12);
      uint4 q0, q1;
      q0.x = pkbf(a0.x, a0.y); q0.y = pkbf(a0.z, a0.w);
      q0.z = pkbf(a1.x, a1.y); q0.w = pkbf(a1.z, a1.w);
      q1.x = pkbf(a2.x, a2.y); q1.y = pkbf(a2.z, a2.w);
      q1.z = pkbf(a3.x, a3.y); q1.w = pkbf(a3.z, a3.w);
      int b0 = (row * 128 + c0 * 2)      ^ ((row & 7) << 4);
      int b1 = (row * 128 + c0 * 2 + 16) ^ ((row & 7) << 4);
      *reinterpret_cast<uint4*>(smem + QA_OFF + b0) = q0;
      *reinterpret_cast<uint4*>(smem + QA_OFF + b1) = q1;
    }
    // stage B: [384][64] via async global->LDS
    #pragma unroll
    for (int it = 0; it < 6; ++it){
      int c = it * 512 + tid;
      int n = c >> 3, p = c & 7;
      int s = p ^ (n & 7);
      glds16(wqb + (size_t)(sec * 384 + n) * 384 + kk * 64 + s * 8,
             smem + QB_OFF + c * 16);
    }
    __syncthreads();
    #pragma unroll
    for (int ks = 0; ks < 2; ++ks){
      const int kEl = ks * 32 + lhi * 8;
      bf16x8 af[4], bf[6];
      #pragma unroll
      for (int mt = 0; mt < 4; ++mt)
        af[mt] = lds_frag(smem, QA_OFF, wr * 64 + mt * 16 + l15, 128, kEl);
      #pragma unroll
      for (int nt = 0; nt < 6; ++nt)
        bf[nt] = lds_frag(smem, QB_OFF, wc * 96 + nt * 16 + l15, 128, kEl);
      #pragma unroll
      for (int mt = 0; mt < 4; ++mt)
        #pragma unroll
        for (int nt = 0; nt < 6; ++nt)
          acc[mt][nt] = __builtin_amdgcn_mfma_f32_16x16x32_bf16(af[mt], bf[nt], acc[mt][nt], 0, 0, 0);
    }
    __syncthreads();
  }

  // epilogue: bias + RoPE (+0.125 scale for q), bf16 store into out slots
  u16* o16 = (u16*)out;
  #pragma unroll
  for (int nt = 0; nt < 6; ++nt){
    const int ch = wc * 96 + nt * 16 + l15;
    const float bias = bq[sec * 384 + ch];
    const int chh = ch & 63;
    const int p   = chh >> 1;
    const int m   = p & 15;
    const bool isR = (p < 16);
    const bool ev  = ((ch & 1) == 0);
    #pragma unroll
    for (int mt = 0; mt < 4; ++mt){
      #pragma unroll
      for (int r = 0; r < 4; ++r){
        const int i = wr * 64 + mt * 16 + lhi * 4 + r;
        float v = acc[mt][nt][r] + bias;
        float o = __shfl_xor(v, 1);
        int pos = isR ? r6 : (6 + (bcol * 128 + i + 6) % 12);
        float cc = tabc[pos * 16 + m], ssn = tabs[pos * 16 + m];
        float nv = ev ? (v * cc - o * ssn) : (o * ssn + v * cc);
        if (sec == 0) nv *= 0.125f;
        o16[(row0 + i) * 768 + sec * 384 + ch] = f2bf(nv);
      }
    }
  }
}

// ============ K3: per-window attention (v recomputed; q,k read from out; 36KB LDS) ============
#define VT3 0        // [64ch][128tok] bf16 stride 256 swz : 16384
#define P3  16384    // [80q][128k]    bf16 stride 256 swz : 20480 -> 36864
__launch_bounds__(320, 4)
__global__ void win_attn(const float* __restrict__ x,
                         const u16* __restrict__ wqb,
                         const float* __restrict__ bq,
                         float* __restrict__ out)
{
  __shared__ __align__(16) unsigned char smem[36864];
  const int tid  = threadIdx.x;
  const int wave = tid >> 6;
  const int lane = tid & 63;
  const int l15  = lane & 15;
  const int lhi  = lane >> 4;

  const int wgid = blockIdx.x;          // b*1024 + wi*32 + wj
  const int bIdx = wgid >> 10;
  const int win  = wgid & 1023;
  const int wi   = win >> 5;
  const int wj   = win & 31;
  const bool maskWin = (wi == 31);

  auto rowof = [&](int t)->int {
    int r = t / 12, c = t - r * 12;
    int hh = wi * 6 + r + 3;  if (hh >= 192) hh -= 192;
    int ww = wj * 12 + c + 6; if (ww >= 384) ww -= 384;
    return (bIdx * 192 + hh) * 384 + ww;
  };
  const int qtok = wave * 16 + l15;     // 0..79
  const int qrow = rowof(qtok);
  int krow[5];
  #pragma unroll
  for (int nt = 0; nt < 5; ++nt) krow[nt] = rowof(nt * 16 + l15);
  const bool tv = (qtok < 72);

  // x fragments in registers (A-operand of v-GEMM)
  bf16x8 xfrag[12];
  {
    const float* xp = x + (size_t)qrow * 384;
    #pragma unroll
    for (int ks = 0; ks < 12; ++ks){
      uint4 q; q.x = 0; q.y = 0; q.z = 0; q.w = 0;
      if (tv){
        float4 f0 = *reinterpret_cast<const float4*>(xp + ks * 32 + lhi * 8);
        float4 f1 = *reinterpret_cast<const float4*>(xp + ks * 32 + lhi * 8 + 4);
        q.x = pkbf(f0.x, f0.y); q.y = pkbf(f0.z, f0.w);
        q.z = pkbf(f1.x, f1.y); q.w = pkbf(f1.z, f1.w);
      }
      FragU f; f.u4 = q; xfrag[ks] = f.bf;
    }
  }

  const u16* o16 = (const u16*)out;
  u16* ao16 = (u16*)out;
  const u16* wv = wqb + 768 * 384;

  float sv[5][4];
  #pragma unroll
  for (int a2 = 0; a2 < 5; ++a2)
    #pragma unroll
    for (int b2 = 0; b2 < 4; ++b2) sv[a2][b2] = 0.0f;

  for (int h = 0; h < 6; ++h){
    // ---- v-GEMM: C[tok][ch] from xfrag x global wv B-frags; store transposed vt[ch][tok]
    {
      f32x4 vacc[4];
      #pragma unroll
      for (int nt = 0; nt < 4; ++nt) vacc[nt] = 0.0f;
      #pragma unroll
      for (int ks = 0; ks < 12; ++ks){
        const int kEl = ks * 32 + lhi * 8;
        #pragma unroll
        for (int nt = 0; nt < 4; ++nt){
          FragU f;
          f.u4 = *reinterpret_cast<const uint4*>(wv + (size_t)(h * 64 + nt * 16 + l15) * 384 + kEl);
          vacc[nt] = __builtin_amdgcn_mfma_f32_16x16x32_bf16(xfrag[ks], f.bf, vacc[nt], 0, 0, 0);
        }
      }
      #pragma unroll
      for (int nt = 0; nt < 4; ++nt){
        const int chl = nt * 16 + l15;
        const float bv = bq[768 + h * 64 + chl];
        const int t0 = wave * 16 + lhi * 4;
        uint2 pk;
        pk.x = pkbf(vacc[nt][0] + bv, vacc[nt][1] + bv);
        pk.y = pkbf(vacc[nt][2] + bv, vacc[nt][3] + bv);
        int byte = (chl * 256 + t0 * 2) ^ ((chl & 7) << 4);
        *reinterpret_cast<uint2*>(smem + VT3 + byte) = pk;
      }
    }

    // ---- QK^T: per-lane global frags (no LDS). C[i=k][j=q].
    f32x4 pf[5];
    #pragma unroll
    for (int nt = 0; nt < 5; ++nt) pf[nt] = 0.0f;
    #pragma unroll
    for (int ks = 0; ks < 2; ++ks){
      const int kEl = ks * 32 + lhi * 8;
      FragU qf;
      qf.u4 = *reinterpret_cast<const uint4*>(o16 + (size_t)qrow * 768 + h * 64 + kEl);
      #pragma unroll
      for (int nt = 0; nt < 5; ++nt){
        FragU kf;
        kf.u4 = *reinterpret_cast<const uint4*>(o16 + (size_t)krow[nt] * 768 + 384 + h * 64 + kEl);
        pf[nt] = __builtin_amdgcn_mfma_f32_16x16x32_bf16(kf.bf, qf.bf, pf[nt], 0, 0, 0);
      }
    }

    // ---- mask + softmax over k (lanes: lhi spans k; shfl 16/32)
    float mx = -1e30f;
    #pragma unroll
    for (int nt = 0; nt < 5; ++nt)
      #pragma unroll
      for (int r = 0; r < 4; ++r){
        const int kk2 = nt * 16 + lhi * 4 + r;
        bool valid = (kk2 < 72) && (!maskWin || ((kk2 < 36) == (qtok < 36)));
        float val = valid ? pf[nt][r] : -1e30f;
        pf[nt][r] = val;
        mx = fmaxf(mx, val);
      }
    mx = fmaxf(mx, __shfl_xor(mx, 16));
    mx = fmaxf(mx, __shfl_xor(mx, 32));
    float sm = 0.0f;
    #pragma unroll
    for (int nt = 0; nt < 5; ++nt)
      #pragma unroll
      for (int r = 0; r < 4; ++r){
        float e = __expf(pf[nt][r] - mx);
        pf[nt][r] = e; sm += e;
      }
    sm += __shfl_xor(sm, 16);
    sm += __shfl_xor(sm, 32);
    const float inv = 1.0f / sm;
    #pragma unroll
    for (int nt = 0; nt < 5; ++nt)
      #pragma unroll
      for (int r = 0; r < 4; ++r){
        float pv2 = pf[nt][r] * inv;
        pf[nt][r] = pv2;
        sv[nt][r] += pv2;
      }

    // ---- P store [q][k] (packed along k) + zero pad cols 80..95
    #pragma unroll
    for (int nt = 0; nt < 5; ++nt){
      const int k0 = nt * 16 + lhi * 4;
      uint2 pk;
      pk.x = pkbf(pf[nt][0], pf[nt][1]);
      pk.y = pkbf(pf[nt][2], pf[nt][3]);
      int byte = (qtok * 256 + k0 * 2) ^ ((qtok & 7) << 4);
      *reinterpret_cast<uint2*>(smem + P3 + byte) = pk;
    }
    {
      int byte = (qtok * 256 + (80 + lhi * 4) * 2) ^ ((qtok & 7) << 4);
      uint2 z; z.x = 0; z.y = 0;
      *reinterpret_cast<uint2*>(smem + P3 + byte) = z;
    }
    __syncthreads();                    // vt + P visible

    // ---- PV: C[i=ch][j=q]; write attnout bf16 over q-slots of own row
    f32x4 oacc[4];
    #pragma unroll
    for (int nt = 0; nt < 4; ++nt) oacc[nt] = 0.0f;
    #pragma unroll
    for (int ks = 0; ks < 3; ++ks){
      const int kEl = ks * 32 + lhi * 8;
      bf16x8 pfr = lds_frag(smem, P3, qtok, 256, kEl);
      #pragma unroll
      for (int nt = 0; nt < 4; ++nt){
        bf16x8 vf = lds_frag(smem, VT3, nt * 16 + l15, 256, kEl);
        oacc[nt] = __builtin_amdgcn_mfma_f32_16x16x32_bf16(vf, pfr, oacc[nt], 0, 0, 0);
      }
    }
    if (tv){
      u16* ao = ao16 + (size_t)qrow * 768 + h * 64;
      #pragma unroll
      for (int nt = 0; nt < 4; ++nt){
        uint2 pk;
        pk.x = pkbf(oacc[nt][0], oacc[nt][1]);
        pk.y = pkbf(oacc[nt][2], oacc[nt][3]);
        *reinterpret_cast<uint2*>(ao + nt * 16 + lhi * 4) = pk;
      }
    }
    __syncthreads();                    // vt + P consumed
  } // heads

  // ---- save_attn = mean over heads
  if (tv){
    float* so = out + 56623104ull + (size_t)wgid * 5184 + (size_t)qtok * 72;
    const float c6 = 1.0f / 6.0f;
    #pragma unroll
    for (int nt = 0; nt < 4; ++nt){
      float4 v4; v4.x = sv[nt][0]*c6; v4.y = sv[nt][1]*c6; v4.z = sv[nt][2]*c6; v4.w = sv[nt][3]*c6;
      *reinterpret_cast<float4*>(so + nt * 16 + lhi * 4) = v4;
    }
    if (lhi < 2){
      float4 v4; v4.x = sv[4][0]*c6; v4.y = sv[4][1]*c6; v4.z = sv[4][2]*c6; v4.w = sv[4][3]*c6;
      *reinterpret_cast<float4*>(so + 64 + lhi * 4) = v4;
    }
  }
}

// ============ K4: out-projection GEMM, in-place per-row ============
#define A2_OFF 0        // [128][64] bf16 stride 128, swz : 16384
#define B2_OFF 16384    // [384][64] bf16 stride 128, swz : 49152
#define SMEM2  65536
__launch_bounds__(512, 2)
__global__ void proj_gemm(const u16* __restrict__ wpb, const float* __restrict__ bp,
                          float* __restrict__ out)
{
  __shared__ __align__(16) unsigned char smem[SMEM2];
  unsigned char* base = smem;

  const int tid  = threadIdx.x;
  const int wave = tid >> 6;
  const int lane = tid & 63;
  const int l15  = lane & 15;
  const int lhi  = lane >> 4;
  const int wr   = wave >> 2;
  const int wc   = wave & 3;
  const size_t row0 = (size_t)blockIdx.x * 128;
  const u16* aog = (const u16*)out;

  f32x4 acc[4][6];
  #pragma unroll
  for (int mt = 0; mt < 4; ++mt)
    #pragma unroll
    for (int nt = 0; nt < 6; ++nt) acc[mt][nt] = 0.0f;

  for (int kk = 0; kk < 6; ++kk){
    #pragma unroll
    for (int it = 0; it < 2; ++it){
      int c = it * 512 + wave * 64 + lane;
      int rrow = c >> 3, p = c & 7;
      int s = p ^ (rrow & 7);
      glds16(aog + (row0 + rrow) * 768 + kk * 64 + s * 8,
             base + A2_OFF + (it * 512 + wave * 64) * 16);
    }
    #pragma unroll
    for (int it = 0; it < 6; ++it){
      int c = it * 512 + wave * 64 + lane;
      int n = c >> 3, p = c & 7;
      int s = p ^ (n & 7);
      glds16(wpb + (size_t)n * 384 + kk * 64 + s * 8,
             base + B2_OFF + (it * 512 + wave * 64) * 16);
    }
    __syncthreads();
    #pragma unroll
    for (int ks = 0; ks < 2; ++ks){
      const int kEl = ks * 32 + lhi * 8;
      bf16x8 af[4], bf[6];
      #pragma unroll
      for (int mt = 0; mt < 4; ++mt)
        af[mt] = lds_frag(base, A2_OFF, wr * 64 + mt * 16 + l15, 128, kEl);
      #pragma unroll
      for (int nt = 0; nt < 6; ++nt)
        bf[nt] = lds_frag(base, B2_OFF, wc * 96 + nt * 16 + l15, 128, kEl);
      #pragma unroll
      for (int mt = 0; mt < 4; ++mt)
        #pragma unroll
        for (int nt = 0; nt < 6; ++nt)
          acc[mt][nt] = __builtin_amdgcn_mfma_f32_16x16x32_bf16(af[mt], bf[nt], acc[mt][nt], 0, 0, 0);
    }
    __syncthreads();
  }

  float bpv[6];
  #pragma unroll
  for (int nt = 0; nt < 6; ++nt) bpv[nt] = bp[wc * 96 + nt * 16 + l15];
  #pragma unroll
  for (int mt = 0; mt < 4; ++mt)
    #pragma unroll
    for (int nt = 0; nt < 6; ++nt){
      const int ch = wc * 96 + nt * 16 + l15;
      #pragma unroll
      for (int r = 0; r < 4; ++r){
        size_t grow = row0 + wr * 64 + mt * 16 + lhi * 4 + r;
        out[grow * 384 + ch] = acc[mt][nt][r] + bpv[nt];
      }
    }
}

extern "C" void kernel_launch(void* const* d_in, const int* in_sizes, int n_in,
                              void* d_out, int out_size, void* d_ws, size_t ws_size,
                              hipStream_t stream)
{
  const float* x  = (const float*)d_in[0];
  const float* wq = (const float*)d_in[1];
  const float* bq = (const float*)d_in[2];
  const float* wp = (const float*)d_in[3];
  const float* bp = (const float*)d_in[4];
  float* out = (float*)d_out;

  u16* wqb = (u16*)d_ws;                              // 442368 bf16
  u16* wpb = (u16*)((char*)d_ws + 442368 * 2);        // 147456 bf16

  prep_weights<<<1728, 256, 0, stream>>>(wq, wp, wqb, wpb);
  qk_gemm<<<dim3(1152, 2), 512, 0, stream>>>(x, wqb, bq, out);
  win_attn<<<2048, 320, 0, stream>>>(x, wqb, bq, out);
  proj_gemm<<<1152, 512, 0, stream>>>(wpb, bp, out);
}

// Round 4
// 692.043 us; speedup vs baseline: 2.7533x; 1.6919x over previous
//
#include <hip/hip_runtime.h>

typedef __attribute__((ext_vector_type(8))) __bf16 bf16x8;
typedef __attribute__((ext_vector_type(4))) float f32x4;
typedef unsigned short u16;
typedef unsigned int u32;

__device__ __forceinline__ u16 f2bf(float x){
  u32 u = __float_as_uint(x);
  return (u16)((u + 0x7fffu + ((u >> 16) & 1u)) >> 16);
}
__device__ __forceinline__ u32 pkbf(float lo, float hi){
  u32 r; asm("v_cvt_pk_bf16_f32 %0, %1, %2" : "=v"(r) : "v"(lo), "v"(hi)); return r;
}

union FragU { uint4 u4; bf16x8 bf; };

__device__ __forceinline__ bf16x8 lds_frag(const unsigned char* smem, int off, int row, int strideB, int kElem){
  int byte = (row * strideB + kElem * 2) ^ ((row & 7) << 4);
  FragU f; f.u4 = *reinterpret_cast<const uint4*>(smem + off + byte);
  return f.bf;
}

typedef __attribute__((address_space(3))) unsigned char lds_u8;
typedef __attribute__((address_space(1))) const unsigned char g_u8;
__device__ __forceinline__ void glds16(const void* g, void* l){
  __builtin_amdgcn_global_load_lds((g_u8*)g, (lds_u8*)l, 16, 0, 0);
}

__global__ void prep_weights(const float* __restrict__ wq, const float* __restrict__ wp,
                             u16* __restrict__ wqb, u16* __restrict__ wpb){
  int i = blockIdx.x * 256 + threadIdx.x;
  wqb[i] = f2bf(wq[i]);              // grid sized exactly for 442368
  if (i < 147456) wpb[i] = f2bf(wp[i]);
}

// ============ K2: qkv GEMM. sec 0=q,1=k: bias+RoPE(+scale) -> out row slots.
//              sec 2: bias -> v_ws tiled [win][h][64ch][80tok] bf16. ============
#define QA_OFF 0        // [128][64] bf16 swz : 16384
#define QB_OFF 16384    // [384][64] bf16 swz : 49152 -> 65536
#define QTC    65536    // 288 f32
#define QTS    66688    // 288 f32 -> 67840
__launch_bounds__(512, 2)
__global__ void qkv_gemm(const float* __restrict__ x, const u16* __restrict__ wqb,
                         const float* __restrict__ bq, float* __restrict__ out,
                         u16* __restrict__ vws)
{
  __shared__ __align__(16) unsigned char smem[67840];
  const int tid  = threadIdx.x;
  const int wave = tid >> 6;
  const int lane = tid & 63;
  const int l15  = lane & 15;
  const int lhi  = lane >> 4;
  const int wr   = wave >> 2;           // 0..1 : 64-row half
  const int wc   = wave & 3;            // 0..3 : 96-col quarter
  const int bx   = blockIdx.x;
  const int sec  = blockIdx.y;          // 0=q, 1=k, 2=v
  const size_t row0 = (size_t)bx * 128;
  const int a    = bx / 3;              // global image-row index (0..383)
  const int bcol = bx - 3 * a;
  const int bIm  = a / 192;
  const int hh   = a % 192;
  const int rh   = (hh >= 3) ? hh - 3 : hh + 189;   // rolled row
  const int wi   = rh / 6;
  const int r6   = rh - wi * 6;                      // window-row of all tokens
  const int bwin = bIm * 1024 + wi * 32;

  float* tabc = reinterpret_cast<float*>(smem + QTC);
  float* tabs = reinterpret_cast<float*>(smem + QTS);
  if (tid < 288){
    int pos = tid >> 4, m = tid & 15;
    float pv = (pos < 6) ? (float)pos : (float)(pos - 6);
    float ang = pv * __expf(-(float)m * 0.5756462732485114f); // 10000^(-m/16)
    tabc[tid] = cosf(ang);
    tabs[tid] = sinf(ang);
  }

  f32x4 acc[4][6];
  #pragma unroll
  for (int mt = 0; mt < 4; ++mt)
    #pragma unroll
    for (int nt = 0; nt < 6; ++nt) acc[mt][nt] = 0.0f;

  for (int kk = 0; kk < 6; ++kk){
    // stage A: f32 -> bf16 reg-staging, swizzled [128][64]
    {
      int row = tid >> 2;
      int c0  = (tid & 3) << 4;
      const float* src = x + (row0 + row) * 384 + kk * 64 + c0;
      float4 a0 = *reinterpret_cast<const float4*>(src);
      float4 a1 = *reinterpret_cast<const float4*>(src + 4);
      float4 a2 = *reinterpret_cast<const float4*>(src + 8);
      float4 a3 = *reinterpret_cast<const float4*>(src + 12);
      uint4 q0, q1;
      q0.x = pkbf(a0.x, a0.y); q0.y = pkbf(a0.z, a0.w);
      q0.z = pkbf(a1.x, a1.y); q0.w = pkbf(a1.z, a1.w);
      q1.x = pkbf(a2.x, a2.y); q1.y = pkbf(a2.z, a2.w);
      q1.z = pkbf(a3.x, a3.y); q1.w = pkbf(a3.z, a3.w);
      int b0 = (row * 128 + c0 * 2)      ^ ((row & 7) << 4);
      int b1 = (row * 128 + c0 * 2 + 16) ^ ((row & 7) << 4);
      *reinterpret_cast<uint4*>(smem + QA_OFF + b0) = q0;
      *reinterpret_cast<uint4*>(smem + QA_OFF + b1) = q1;
    }
    // stage B: [384][64] via async global->LDS
    #pragma unroll
    for (int it = 0; it < 6; ++it){
      int c = it * 512 + tid;
      int n = c >> 3, p = c & 7;
      int s = p ^ (n & 7);
      glds16(wqb + (size_t)(sec * 384 + n) * 384 + kk * 64 + s * 8,
             smem + QB_OFF + c * 16);
    }
    __syncthreads();
    #pragma unroll
    for (int ks = 0; ks < 2; ++ks){
      const int kEl = ks * 32 + lhi * 8;
      bf16x8 af[4], bf[6];
      #pragma unroll
      for (int mt = 0; mt < 4; ++mt)
        af[mt] = lds_frag(smem, QA_OFF, wr * 64 + mt * 16 + l15, 128, kEl);
      #pragma unroll
      for (int nt = 0; nt < 6; ++nt)
        bf[nt] = lds_frag(smem, QB_OFF, wc * 96 + nt * 16 + l15, 128, kEl);
      #pragma unroll
      for (int mt = 0; mt < 4; ++mt)
        #pragma unroll
        for (int nt = 0; nt < 6; ++nt)
          acc[mt][nt] = __builtin_amdgcn_mfma_f32_16x16x32_bf16(af[mt], bf[nt], acc[mt][nt], 0, 0, 0);
    }
    __syncthreads();
  }

  if (sec < 2){
    // epilogue: bias + RoPE (+0.125 scale for q), bf16 store into out slots
    u16* o16 = (u16*)out;
    #pragma unroll
    for (int nt = 0; nt < 6; ++nt){
      const int ch = wc * 96 + nt * 16 + l15;
      const float bias = bq[sec * 384 + ch];
      const int chh = ch & 63;
      const int p   = chh >> 1;
      const int m   = p & 15;
      const bool isR = (p < 16);
      const bool ev  = ((ch & 1) == 0);
      #pragma unroll
      for (int mt = 0; mt < 4; ++mt){
        #pragma unroll
        for (int r = 0; r < 4; ++r){
          const int i = wr * 64 + mt * 16 + lhi * 4 + r;
          float v = acc[mt][nt][r] + bias;
          float o = __shfl_xor(v, 1);
          int pos = isR ? r6 : (6 + (bcol * 128 + i + 6) % 12);
          float cc = tabc[pos * 16 + m], ssn = tabs[pos * 16 + m];
          float nv = ev ? (v * cc - o * ssn) : (o * ssn + v * cc);
          if (sec == 0) nv *= 0.125f;
          o16[(row0 + i) * 768 + sec * 384 + ch] = f2bf(nv);
        }
      }
    }
  } else {
    // v epilogue: bias, store into v_ws [win][h][chh][tok] (quads of 4 tokens)
    #pragma unroll
    for (int mt = 0; mt < 4; ++mt){
      const int ww2 = bcol * 128 + wr * 64 + mt * 16 + lhi * 4;  // first tok of quad
      const int rw  = (ww2 >= 6) ? ww2 - 6 : ww2 + 378;
      const int wj  = rw / 12;
      const int c0  = rw - wj * 12;            // in {2,6,10}
      const int tokb = r6 * 12;
      #pragma unroll
      for (int nt = 0; nt < 6; ++nt){
        const int ch  = wc * 96 + nt * 16 + l15;
        const int h   = ch >> 6;
        const int chh = ch & 63;
        const float bv = bq[768 + ch];
        u32 lo = pkbf(acc[mt][nt][0] + bv, acc[mt][nt][1] + bv);
        u32 hi = pkbf(acc[mt][nt][2] + bv, acc[mt][nt][3] + bv);
        u16* basep = vws + ((size_t)(bwin + wj) * 6 + h) * 5120 + chh * 80;
        if (c0 != 10){
          *reinterpret_cast<u32*>(basep + tokb + c0)     = lo;
          *reinterpret_cast<u32*>(basep + tokb + c0 + 2) = hi;
        } else {
          *reinterpret_cast<u32*>(basep + tokb + 10) = lo;
          const int wj1 = (wj == 31) ? 0 : wj + 1;
          *reinterpret_cast<u32*>(vws + ((size_t)(bwin + wj1) * 6 + h) * 5120 + chh * 80 + tokb) = hi;
        }
      }
    }
  }
}

// ============ K3 v4: per-window attention, fully LDS-staged via glds16 ============
// LDS: QH [80][64] swz (10240) | KH [80][64] swz (10240) | VT [64][80] raw (10240)
#define QH4 0
#define KH4 10240
#define VT4 20480
#define SMEM4 30720
__launch_bounds__(320, 5)
__global__ void win_attn4(const u16* __restrict__ vws,
                          float* __restrict__ out)
{
  __shared__ __align__(16) unsigned char smem[SMEM4];
  const int tid  = threadIdx.x;
  const int wave = tid >> 6;
  const int lane = tid & 63;
  const int l15  = lane & 15;
  const int lhi  = lane >> 4;

  const int bid  = blockIdx.x;
  const int wgid = (bid & 7) * 256 + (bid >> 3);   // XCD swizzle (2048 = 8*256)
  const int bIdx = wgid >> 10;
  const int win  = wgid & 1023;
  const int wi   = win >> 5;
  const int wj   = win & 31;
  const bool maskWin = (wi == 31);

  auto rowof = [&](int t)->size_t {
    int r = t / 12, c = t - r * 12;
    int hh = wi * 6 + r + 3;  if (hh >= 192) hh -= 192;
    int ww = wj * 12 + c + 6; if (ww >= 384) ww -= 384;
    return ((size_t)bIdx * 192 + hh) * 384 + ww;
  };
  const int qtok = wave * 16 + l15;     // 0..79
  const bool tv = (qtok < 72);
  const size_t qrow = rowof(tv ? qtok : 71);

  const u16* o16c = (const u16*)out;
  u16* ao16 = (u16*)out;
  const u16* vsl = vws + (size_t)win * 30720 + (size_t)bIdx * 31457280; // win*6*5120

  float sv[5][4];
  #pragma unroll
  for (int a2 = 0; a2 < 5; ++a2)
    #pragma unroll
    for (int b2 = 0; b2 < 4; ++b2) sv[a2][b2] = 0.0f;

  for (int h = 0; h < 6; ++h){
    // ---- stage q,k (swizzled src) and v (linear) : 1920 glds16 chunks ----
    #pragma unroll
    for (int it = 0; it < 2; ++it){
      int c = it * 320 + tid;           // 0..639
      int t = c >> 3, p = c & 7;
      size_t row = rowof(t < 72 ? t : 71);
      int s = (p ^ (t & 7)) << 3;
      glds16(o16c + row * 768 + h * 64 + s,       smem + QH4 + c * 16);
      glds16(o16c + row * 768 + 384 + h * 64 + s, smem + KH4 + c * 16);
      glds16(vsl + (size_t)h * 5120 + c * 8,      smem + VT4 + c * 16);
    }
    __syncthreads();                    // stage visible

    // ---- QK^T: C[i=k][j=q] ----
    f32x4 pf[5];
    #pragma unroll
    for (int nt = 0; nt < 5; ++nt) pf[nt] = 0.0f;
    #pragma unroll
    for (int ks = 0; ks < 2; ++ks){
      const int kEl = ks * 32 + lhi * 8;
      bf16x8 qf = lds_frag(smem, QH4, qtok, 128, kEl);
      #pragma unroll
      for (int nt = 0; nt < 5; ++nt){
        bf16x8 kf = lds_frag(smem, KH4, nt * 16 + l15, 128, kEl);
        pf[nt] = __builtin_amdgcn_mfma_f32_16x16x32_bf16(kf, qf, pf[nt], 0, 0, 0);
      }
    }

    // ---- mask + softmax over k ----
    float mx = -1e30f;
    #pragma unroll
    for (int nt = 0; nt < 5; ++nt)
      #pragma unroll
      for (int r = 0; r < 4; ++r){
        const int kk2 = nt * 16 + lhi * 4 + r;
        bool valid = (kk2 < 72) && (!maskWin || ((kk2 < 36) == (qtok < 36)));
        float val = valid ? pf[nt][r] : -1e30f;
        pf[nt][r] = val;
        mx = fmaxf(mx, val);
      }
    mx = fmaxf(mx, __shfl_xor(mx, 16));
    mx = fmaxf(mx, __shfl_xor(mx, 32));
    float sm = 0.0f;
    #pragma unroll
    for (int nt = 0; nt < 5; ++nt)
      #pragma unroll
      for (int r = 0; r < 4; ++r){
        float e = __expf(pf[nt][r] - mx);
        pf[nt][r] = e; sm += e;
      }
    sm += __shfl_xor(sm, 16);
    sm += __shfl_xor(sm, 32);
    const float inv = 1.0f / sm;
    u32 pp[5][2];                       // packed bf16 pairs: P[k..k+1][q=l15]
    #pragma unroll
    for (int nt = 0; nt < 5; ++nt){
      float p0 = pf[nt][0] * inv, p1 = pf[nt][1] * inv;
      float p2 = pf[nt][2] * inv, p3 = pf[nt][3] * inv;
      sv[nt][0] += p0; sv[nt][1] += p1; sv[nt][2] += p2; sv[nt][3] += p3;
      pp[nt][0] = pkbf(p0, p1);
      pp[nt][1] = pkbf(p2, p3);
    }

    // ---- PV: C[i=ch][j=q]; B-frags of P built by shfl (no LDS, no barrier) ----
    f32x4 oacc[4];
    #pragma unroll
    for (int nt = 0; nt < 4; ++nt) oacc[nt] = 0.0f;
    #pragma unroll
    for (int ks = 0; ks < 3; ++ks){
      FragU pb;
      u32 w[4];
      #pragma unroll
      for (int w_ = 0; w_ < 4; ++w_){
        int srcLane = l15 + 16 * ((lane >> 4 & 1) * 2 + (w_ >> 1));
        u32 c0 = __shfl(pp[ks * 2][w_ & 1], srcLane);
        u32 c1 = (ks * 2 + 1 < 5) ? __shfl(pp[ks * 2 + 1][w_ & 1], srcLane) : 0u;
        w[w_] = (lhi & 2) ? c1 : c0;
      }
      pb.u4.x = w[0]; pb.u4.y = w[1]; pb.u4.z = w[2]; pb.u4.w = w[3];
      const int kEl = ks * 32 + lhi * 8;
      #pragma unroll
      for (int nt = 0; nt < 4; ++nt){
        FragU vf;
        vf.u4 = *reinterpret_cast<const uint4*>(smem + VT4 + (nt * 16 + l15) * 160 + kEl * 2);
        oacc[nt] = __builtin_amdgcn_mfma_f32_16x16x32_bf16(vf.bf, pb.bf, oacc[nt], 0, 0, 0);
      }
    }
    if (tv){
      u16* ao = ao16 + qrow * 768 + h * 64;
      #pragma unroll
      for (int nt = 0; nt < 4; ++nt){
        uint2 pk;
        pk.x = pkbf(oacc[nt][0], oacc[nt][1]);
        pk.y = pkbf(oacc[nt][2], oacc[nt][3]);
        *reinterpret_cast<uint2*>(ao + nt * 16 + lhi * 4) = pk;
      }
    }
    __syncthreads();                    // all LDS reads done before next stage
  } // heads

  // ---- save_attn = mean over heads: so[q*72 + k] ----
  if (tv){
    float* so = out + 56623104ull + (size_t)wgid * 5184 + (size_t)qtok * 72;
    const float c6 = 1.0f / 6.0f;
    #pragma unroll
    for (int nt = 0; nt < 4; ++nt){
      float4 v4; v4.x = sv[nt][0]*c6; v4.y = sv[nt][1]*c6; v4.z = sv[nt][2]*c6; v4.w = sv[nt][3]*c6;
      *reinterpret_cast<float4*>(so + nt * 16 + lhi * 4) = v4;
    }
    if (lhi < 2){
      float4 v4; v4.x = sv[4][0]*c6; v4.y = sv[4][1]*c6; v4.z = sv[4][2]*c6; v4.w = sv[4][3]*c6;
      *reinterpret_cast<float4*>(so + 64 + lhi * 4) = v4;
    }
  }
}

// ============ K3 fallback (ws too small): v recomputed per window ============
#define VT3 0        // [64ch][128tok] bf16 stride 256 swz : 16384
#define P3  16384    // [80q][128k]    bf16 stride 256 swz : 20480 -> 36864
__launch_bounds__(320, 4)
__global__ void win_attn_fb(const float* __restrict__ x,
                            const u16* __restrict__ wqb,
                            const float* __restrict__ bq,
                            float* __restrict__ out)
{
  __shared__ __align__(16) unsigned char smem[36864];
  const int tid  = threadIdx.x;
  const int wave = tid >> 6;
  const int lane = tid & 63;
  const int l15  = lane & 15;
  const int lhi  = lane >> 4;

  const int wgid = blockIdx.x;
  const int bIdx = wgid >> 10;
  const int win  = wgid & 1023;
  const int wi   = win >> 5;
  const int wj   = win & 31;
  const bool maskWin = (wi == 31);

  auto rowof = [&](int t)->int {
    int r = t / 12, c = t - r * 12;
    int hh = wi * 6 + r + 3;  if (hh >= 192) hh -= 192;
    int ww = wj * 12 + c + 6; if (ww >= 384) ww -= 384;
    return (bIdx * 192 + hh) * 384 + ww;
  };
  const int qtok = wave * 16 + l15;
  const int qrow = rowof(qtok < 72 ? qtok : 71);
  int krow[5];
  #pragma unroll
  for (int nt = 0; nt < 5; ++nt) krow[nt] = rowof(nt * 16 + l15 < 72 ? nt * 16 + l15 : 71);
  const bool tv = (qtok < 72);

  bf16x8 xfrag[12];
  {
    const float* xp = x + (size_t)qrow * 384;
    #pragma unroll
    for (int ks = 0; ks < 12; ++ks){
      uint4 q; q.x = 0; q.y = 0; q.z = 0; q.w = 0;
      if (tv){
        float4 f0 = *reinterpret_cast<const float4*>(xp + ks * 32 + lhi * 8);
        float4 f1 = *reinterpret_cast<const float4*>(xp + ks * 32 + lhi * 8 + 4);
        q.x = pkbf(f0.x, f0.y); q.y = pkbf(f0.z, f0.w);
        q.z = pkbf(f1.x, f1.y); q.w = pkbf(f1.z, f1.w);
      }
      FragU f; f.u4 = q; xfrag[ks] = f.bf;
    }
  }

  const u16* o16 = (const u16*)out;
  u16* ao16 = (u16*)out;
  const u16* wv = wqb + 768 * 384;

  float sv[5][4];
  #pragma unroll
  for (int a2 = 0; a2 < 5; ++a2)
    #pragma unroll
    for (int b2 = 0; b2 < 4; ++b2) sv[a2][b2] = 0.0f;

  for (int h = 0; h < 6; ++h){
    {
      f32x4 vacc[4];
      #pragma unroll
      for (int nt = 0; nt < 4; ++nt) vacc[nt] = 0.0f;
      #pragma unroll
      for (int ks = 0; ks < 12; ++ks){
        const int kEl = ks * 32 + lhi * 8;
        #pragma unroll
        for (int nt = 0; nt < 4; ++nt){
          FragU f;
          f.u4 = *reinterpret_cast<const uint4*>(wv + (size_t)(h * 64 + nt * 16 + l15) * 384 + kEl);
          vacc[nt] = __builtin_amdgcn_mfma_f32_16x16x32_bf16(xfrag[ks], f.bf, vacc[nt], 0, 0, 0);
        }
      }
      #pragma unroll
      for (int nt = 0; nt < 4; ++nt){
        const int chl = nt * 16 + l15;
        const float bv = bq[768 + h * 64 + chl];
        const int t0 = wave * 16 + lhi * 4;
        uint2 pk;
        pk.x = pkbf(vacc[nt][0] + bv, vacc[nt][1] + bv);
        pk.y = pkbf(vacc[nt][2] + bv, vacc[nt][3] + bv);
        int byte = (chl * 256 + t0 * 2) ^ ((chl & 7) << 4);
        *reinterpret_cast<uint2*>(smem + VT3 + byte) = pk;
      }
    }

    f32x4 pf[5];
    #pragma unroll
    for (int nt = 0; nt < 5; ++nt) pf[nt] = 0.0f;
    #pragma unroll
    for (int ks = 0; ks < 2; ++ks){
      const int kEl = ks * 32 + lhi * 8;
      FragU qf;
      qf.u4 = *reinterpret_cast<const uint4*>(o16 + (size_t)qrow * 768 + h * 64 + kEl);
      #pragma unroll
      for (int nt = 0; nt < 5; ++nt){
        FragU kf;
        kf.u4 = *reinterpret_cast<const uint4*>(o16 + (size_t)krow[nt] * 768 + 384 + h * 64 + kEl);
        pf[nt] = __builtin_amdgcn_mfma_f32_16x16x32_bf16(kf.bf, qf.bf, pf[nt], 0, 0, 0);
      }
    }

    float mx = -1e30f;
    #pragma unroll
    for (int nt = 0; nt < 5; ++nt)
      #pragma unroll
      for (int r = 0; r < 4; ++r){
        const int kk2 = nt * 16 + lhi * 4 + r;
        bool valid = (kk2 < 72) && (!maskWin || ((kk2 < 36) == (qtok < 36)));
        float val = valid ? pf[nt][r] : -1e30f;
        pf[nt][r] = val;
        mx = fmaxf(mx, val);
      }
    mx = fmaxf(mx, __shfl_xor(mx, 16));
    mx = fmaxf(mx, __shfl_xor(mx, 32));
    float sm = 0.0f;
    #pragma unroll
    for (int nt = 0; nt < 5; ++nt)
      #pragma unroll
      for (int r = 0; r < 4; ++r){
        float e = __expf(pf[nt][r] - mx);
        pf[nt][r] = e; sm += e;
      }
    sm += __shfl_xor(sm, 16);
    sm += __shfl_xor(sm, 32);
    const float inv = 1.0f / sm;
    #pragma unroll
    for (int nt = 0; nt < 5; ++nt)
      #pragma unroll
      for (int r = 0; r < 4; ++r){
        float pv2 = pf[nt][r] * inv;
        pf[nt][r] = pv2;
        sv[nt][r] += pv2;
      }

    #pragma unroll
    for (int nt = 0; nt < 5; ++nt){
      const int k0 = nt * 16 + lhi * 4;
      uint2 pk;
      pk.x = pkbf(pf[nt][0], pf[nt][1]);
      pk.y = pkbf(pf[nt][2], pf[nt][3]);
      int byte = (qtok * 256 + k0 * 2) ^ ((qtok & 7) << 4);
      *reinterpret_cast<uint2*>(smem + P3 + byte) = pk;
    }
    {
      int byte = (qtok * 256 + (80 + lhi * 4) * 2) ^ ((qtok & 7) << 4);
      uint2 z; z.x = 0; z.y = 0;
      *reinterpret_cast<uint2*>(smem + P3 + byte) = z;
    }
    __syncthreads();

    f32x4 oacc[4];
    #pragma unroll
    for (int nt = 0; nt < 4; ++nt) oacc[nt] = 0.0f;
    #pragma unroll
    for (int ks = 0; ks < 3; ++ks){
      const int kEl = ks * 32 + lhi * 8;
      bf16x8 pfr = lds_frag(smem, P3, qtok, 256, kEl);
      #pragma unroll
      for (int nt = 0; nt < 4; ++nt){
        bf16x8 vf = lds_frag(smem, VT3, nt * 16 + l15, 256, kEl);
        oacc[nt] = __builtin_amdgcn_mfma_f32_16x16x32_bf16(vf, pfr, oacc[nt], 0, 0, 0);
      }
    }
    if (tv){
      u16* ao = ao16 + (size_t)qrow * 768 + h * 64;
      #pragma unroll
      for (int nt = 0; nt < 4; ++nt){
        uint2 pk;
        pk.x = pkbf(oacc[nt][0], oacc[nt][1]);
        pk.y = pkbf(oacc[nt][2], oacc[nt][3]);
        *reinterpret_cast<uint2*>(ao + nt * 16 + lhi * 4) = pk;
      }
    }
    __syncthreads();
  }

  if (tv){
    float* so = out + 56623104ull + (size_t)wgid * 5184 + (size_t)qtok * 72;
    const float c6 = 1.0f / 6.0f;
    #pragma unroll
    for (int nt = 0; nt < 4; ++nt){
      float4 v4; v4.x = sv[nt][0]*c6; v4.y = sv[nt][1]*c6; v4.z = sv[nt][2]*c6; v4.w = sv[nt][3]*c6;
      *reinterpret_cast<float4*>(so + nt * 16 + lhi * 4) = v4;
    }
    if (lhi < 2){
      float4 v4; v4.x = sv[4][0]*c6; v4.y = sv[4][1]*c6; v4.z = sv[4][2]*c6; v4.w = sv[4][3]*c6;
      *reinterpret_cast<float4*>(so + 64 + lhi * 4) = v4;
    }
  }
}

// ============ K4: out-projection GEMM, in-place per-row ============
#define A2_OFF 0        // [128][64] bf16 stride 128, swz : 16384
#define B2_OFF 16384    // [384][64] bf16 stride 128, swz : 49152
#define SMEM2  65536
__launch_bounds__(512, 2)
__global__ void proj_gemm(const u16* __restrict__ wpb, const float* __restrict__ bp,
                          float* __restrict__ out)
{
  __shared__ __align__(16) unsigned char smem[SMEM2];
  unsigned char* base = smem;

  const int tid  = threadIdx.x;
  const int wave = tid >> 6;
  const int lane = tid & 63;
  const int l15  = lane & 15;
  const int lhi  = lane >> 4;
  const int wr   = wave >> 2;
  const int wc   = wave & 3;
  const size_t row0 = (size_t)blockIdx.x * 128;
  const u16* aog = (const u16*)out;

  f32x4 acc[4][6];
  #pragma unroll
  for (int mt = 0; mt < 4; ++mt)
    #pragma unroll
    for (int nt = 0; nt < 6; ++nt) acc[mt][nt] = 0.0f;

  for (int kk = 0; kk < 6; ++kk){
    #pragma unroll
    for (int it = 0; it < 2; ++it){
      int c = it * 512 + wave * 64 + lane;
      int rrow = c >> 3, p = c & 7;
      int s = p ^ (rrow & 7);
      glds16(aog + (row0 + rrow) * 768 + kk * 64 + s * 8,
             base + A2_OFF + (it * 512 + wave * 64) * 16);
    }
    #pragma unroll
    for (int it = 0; it < 6; ++it){
      int c = it * 512 + wave * 64 + lane;
      int n = c >> 3, p = c & 7;
      int s = p ^ (n & 7);
      glds16(wpb + (size_t)n * 384 + kk * 64 + s * 8,
             base + B2_OFF + (it * 512 + wave * 64) * 16);
    }
    __syncthreads();
    #pragma unroll
    for (int ks = 0; ks < 2; ++ks){
      const int kEl = ks * 32 + lhi * 8;
      bf16x8 af[4], bf[6];
      #pragma unroll
      for (int mt = 0; mt < 4; ++mt)
        af[mt] = lds_frag(base, A2_OFF, wr * 64 + mt * 16 + l15, 128, kEl);
      #pragma unroll
      for (int nt = 0; nt < 6; ++nt)
        bf[nt] = lds_frag(base, B2_OFF, wc * 96 + nt * 16 + l15, 128, kEl);
      #pragma unroll
      for (int mt = 0; mt < 4; ++mt)
        #pragma unroll
        for (int nt = 0; nt < 6; ++nt)
          acc[mt][nt] = __builtin_amdgcn_mfma_f32_16x16x32_bf16(af[mt], bf[nt], acc[mt][nt], 0, 0, 0);
    }
    __syncthreads();
  }

  float bpv[6];
  #pragma unroll
  for (int nt = 0; nt < 6; ++nt) bpv[nt] = bp[wc * 96 + nt * 16 + l15];
  #pragma unroll
  for (int mt = 0; mt < 4; ++mt)
    #pragma unroll
    for (int nt = 0; nt < 6; ++nt){
      const int ch = wc * 96 + nt * 16 + l15;
      #pragma unroll
      for (int r = 0; r < 4; ++r){
        size_t grow = row0 + wr * 64 + mt * 16 + lhi * 4 + r;
        out[grow * 384 + ch] = acc[mt][nt][r] + bpv[nt];
      }
    }
}

extern "C" void kernel_launch(void* const* d_in, const int* in_sizes, int n_in,
                              void* d_out, int out_size, void* d_ws, size_t ws_size,
                              hipStream_t stream)
{
  const float* x  = (const float*)d_in[0];
  const float* wq = (const float*)d_in[1];
  const float* bq = (const float*)d_in[2];
  const float* wp = (const float*)d_in[3];
  const float* bp = (const float*)d_in[4];
  float* out = (float*)d_out;

  u16* wqb = (u16*)d_ws;                              // 442368 bf16
  u16* wpb = (u16*)((char*)d_ws + 442368 * 2);        // 147456 bf16
  u16* vws = (u16*)((char*)d_ws + 1179648);           // 2048*6*5120 bf16 (125.8 MB)

  const bool big = ws_size >= 127008768ull;           // weights + v_ws

  prep_weights<<<1728, 256, 0, stream>>>(wq, wp, wqb, wpb);
  if (big){
    qkv_gemm<<<dim3(1152, 3), 512, 0, stream>>>(x, wqb, bq, out, vws);
    win_attn4<<<2048, 320, 0, stream>>>(vws, out);
  } else {
    qkv_gemm<<<dim3(1152, 2), 512, 0, stream>>>(x, wqb, bq, out, vws);
    win_attn_fb<<<2048, 320, 0, stream>>>(x, wqb, bq, out);
  }
  proj_gemm<<<1152, 512, 0, stream>>>(wpb, bp, out);
}